// Round 6
// baseline (6789.696 us; speedup 1.0000x reference)
//
#include <hip/hip_runtime.h>
#include <cstdint>

typedef _Float16 f16;
typedef f16      f16x8 __attribute__((ext_vector_type(8)));
typedef float    f32x4 __attribute__((ext_vector_type(4)));
typedef uint32_t u32;
typedef u32      u32x4 __attribute__((ext_vector_type(4)));

#define NB    32
#define TT    1024
#define DD    512
#define HH    512
#define NBHH  (NB*HH)
#define NWG   64

__device__ __forceinline__ float fsig(float x) {
    return __builtin_amdgcn_rcpf(1.0f + __expf(-x));
}
__device__ __forceinline__ float ftanh(float x) {
    return 1.0f - 2.0f * __builtin_amdgcn_rcpf(__expf(2.0f * x) + 1.0f);
}

// ---- setup kernels -------------------------------------------------------

__global__ void k_cast_x(const float* __restrict__ x, f16* __restrict__ x16) {
    int i = (blockIdx.x * 256 + threadIdx.x) * 8;
    float4 a = *(const float4*)(x + i);
    float4 c = *(const float4*)(x + i + 4);
    f16x8 v;
    v[0] = (f16)a.x; v[1] = (f16)a.y; v[2] = (f16)a.z; v[3] = (f16)a.w;
    v[4] = (f16)c.x; v[5] = (f16)c.y; v[6] = (f16)c.z; v[7] = (f16)c.w;
    *(f16x8*)(x16 + i) = v;
}

// W (512 x 2048 row-major) -> Wp[colp][k] f16; colp = wg*32 + j*4 + gate,
// col2048 = gate*512 + wg*8 + j.
__global__ void k_perm_w(const float* __restrict__ W, f16* __restrict__ Wp) {
    int tid = blockIdx.x * 256 + threadIdx.x;   // 2048*512
    int colp = tid >> 9, k = tid & 511;
    int wg = colp >> 5, c = colp & 31;
    int gate = c & 3, j = c >> 2;
    int col = gate * 512 + wg * 8 + j;
    Wp[tid] = (f16)W[k * 2048 + col];
}

// h0 -> f16 into buffer 1 (consumed at t=0); dispatch-boundary coherence.
__global__ void k_h0(const float* __restrict__ h0, f16* __restrict__ hb) {
    int i = blockIdx.x * 256 + threadIdx.x;     // 32*512
    hb[i] = (f16)h0[i];
}

// ---- persistent LSTM kernel ---------------------------------------------
// 64 WGs x 256 threads. Monotone per-WG flags (64), dual-parity h buffers.
// Producer: h write-through to IF (sc0 sc1) + drain + flag.
// Consumer: flag poll (sc0 sc1) -> agent acquire fence (L2 inv) -> PLAIN
// cached h loads (first WG per XCD pulls from IF, rest hit L2).
// x fed through a 1-step register prefetch pipeline (never on sync chain).

__global__ void __launch_bounds__(256, 1) k_lstm(
    const f16* __restrict__ x16, const f16* __restrict__ Wxp,
    const f16* __restrict__ Whp, const float* __restrict__ bb,
    f16* hbuf, u32* flags, float* __restrict__ out)
{
    __shared__ unsigned char lds_h[32768];   // staged h_{t-1} (swizzled)
    __shared__ u32           lds_pub[256];   // this WG's h_t slice (32n x 8c)
    __shared__ float         lds_out[8192];  // 32 steps x 256 out values

    const int wg  = blockIdx.x;
    const int tid = threadIdx.x;
    const int w   = tid >> 6;
    const int l   = tid & 63;
    const int mt  = w >> 1, nt = w & 1;
    const int lq  = l >> 4, lc = l & 15;

    const int colp = wg * 32 + nt * 16 + lc;   // permuted gate column
    const int gate = lc & 3, j_in = lc >> 2;
    const int hcol = wg * 8 + nt * 4 + j_in;
    const int hc8  = nt * 4 + j_in;            // 0..7 within WG slice
    const float bv = bb[gate * 512 + hcol];

    const int arow   = mt * 16 + lc;           // A-fragment row (batch index)
    const int rm     = l & 3;                  // == gate
    const int n_mine = mt * 16 + lq * 4 + rm;  // row this lane produces

    // Wh and Wx fragments resident in VGPRs for the whole sequence.
    f16x8 Bh[16], Bx[16];
    {
        const f16* ph = Whp + (size_t)colp * 512 + lq * 8;
        const f16* px = Wxp + (size_t)colp * 512 + lq * 8;
        #pragma unroll
        for (int ks = 0; ks < 16; ++ks) {
            Bh[ks] = *(const f16x8*)(ph + ks * 32);
            Bx[ks] = *(const f16x8*)(px + ks * 32);
        }
    }

    const f16* xptr = x16 + (size_t)arow * (TT * DD) + lq * 8;

    // ---- x register-prefetch pipeline: issue t=0 now
    u32x4 xf[16];
    #pragma unroll
    for (int ks = 0; ks < 16; ++ks)
        xf[ks] = *(const u32x4*)(xptr + ks * 32);

    float c_reg[4] = {0.f, 0.f, 0.f, 0.f};

    for (int t = 0; t < TT; ++t) {
        // ---- wait for all 64 per-WG flags (retry = one dword per lane)
        if (t) {
            const u32* fl = flags + l;
            int guard = 0;
            for (;;) {
                u32 f;
                asm volatile("global_load_dword %0, %1, off sc0 sc1"
                             : "=v"(f) : "v"(fl));
                asm volatile("s_waitcnt vmcnt(0)" ::: "memory");
                if (__all(f >= (u32)t) || ++guard > (1 << 20)) break;
            }
        } else {
            asm volatile("s_waitcnt vmcnt(0)" ::: "memory");
        }
        __builtin_amdgcn_sched_barrier(0);
        // ---- agent acquire: invalidate stale L2 copies, then PLAIN loads
        __builtin_amdgcn_fence(__ATOMIC_ACQUIRE, "agent");
        u32x4 hv4[8];
        {
            const char* gp = (const char*)(hbuf + ((t & 1) ? 0 : NBHH)) + tid * 16;
            #pragma unroll
            for (int r = 0; r < 8; ++r)
                hv4[r] = *(const u32x4*)(gp + r * 4096);
        }
        // ---- x_t @ Wx + b from prefetched registers (overlaps h loads)
        f32x4 acc = {bv, bv, bv, bv};
        #pragma unroll
        for (int ks = 0; ks < 16; ++ks)
            acc = __builtin_amdgcn_mfma_f32_16x16x32_f16(
                      __builtin_bit_cast(f16x8, xf[ks]), Bx[ks], acc, 0, 0, 0);
        // ---- stage h into LDS (swizzled), compiler inserts the waitcnt
        {
            const int inrow = (tid & 63) * 16;
            #pragma unroll
            for (int r = 0; r < 8; ++r) {
                int row = (tid >> 6) + 4 * r;
                int off = row * 1024 + (inrow ^ ((row & 7) << 4));
                *(u32x4*)&lds_h[off] = hv4[r];
            }
        }
        __syncthreads();
        // ---- h_{t-1} @ Wh from LDS
        {
            const int swz   = (arow & 7) << 4;
            const int baseA = arow * 1024;
            #pragma unroll
            for (int ks = 0; ks < 16; ++ks) {
                int inrowA = lq * 16 + ks * 64;
                u32x4 a = *(const u32x4*)&lds_h[baseA + (inrowA ^ swz)];
                acc = __builtin_amdgcn_mfma_f32_16x16x32_f16(
                          __builtin_bit_cast(f16x8, a), Bh[ks], acc, 0, 0, 0);
            }
        }
        // ---- gates (quad-redundant c state, intra-quad shuffles)
        float hv = 0.f;
        #pragma unroll
        for (int r = 0; r < 4; ++r) {
            float av = acc[r];
            int base = l & ~3;
            float ai = __shfl(av, base | 0, 64);
            float af = __shfl(av, base | 1, 64);
            float ao = __shfl(av, base | 2, 64);
            float ag = __shfl(av, base | 3, 64);
            float ig = fsig(ai), fg = fsig(af), og = fsig(ao), gg = ftanh(ag);
            float cn = fg * c_reg[r] + ig * gg;
            c_reg[r] = cn;
            float h = og * ftanh(cn);
            if (r == rm) hv = h;
        }
        // ---- stage h_t slice + out value in LDS
        {
            f16 h16 = (f16)hv;
            lds_pub[n_mine * 8 + hc8] = (u32)__builtin_bit_cast(unsigned short, h16);
            lds_out[(t & 31) * 256 + n_mine * 8 + hc8] = hv;
        }
        __syncthreads();
        // ---- wave0: publish WG slice as 32 x 16B write-through, drain, flag
        if (w == 0) {
            if (tid < 32) {
                const u32* pp = lds_pub + tid * 8;
                u32 p0 = (pp[0] & 0xffffu) | (pp[1] << 16);
                u32 p1 = (pp[2] & 0xffffu) | (pp[3] << 16);
                u32 p2 = (pp[4] & 0xffffu) | (pp[5] << 16);
                u32 p3 = (pp[6] & 0xffffu) | (pp[7] << 16);
                u32x4 pv = {p0, p1, p2, p3};
                f16* hdst = hbuf + ((t & 1) ? NBHH : 0) + tid * HH + wg * 8;
                asm volatile("global_store_dwordx4 %0, %1, off sc0 sc1"
                             :: "v"(hdst), "v"(pv) : "memory");
            }
            asm volatile("s_waitcnt vmcnt(0)" ::: "memory");
            if (tid == 0) {
                u32 fv = (u32)(t + 1);
                u32* mf = flags + wg;
                asm volatile("global_store_dword %0, %1, off sc0 sc1"
                             :: "v"(mf), "v"(fv) : "memory");
            }
        }
        // ---- flush 32 steps of out as plain cached float4 (off hot path)
        if ((t & 31) == 31) {
            #pragma unroll
            for (int r2 = 0; r2 < 8; ++r2) {
                int tau = tid + 256 * r2;         // (s*32 + n)*2 + hc4
                int s   = tau >> 6;
                int n2  = (tau >> 1) & 31;
                int hc4 = tau & 1;
                float4 v = *(const float4*)&lds_out[s * 256 + n2 * 8 + hc4 * 4];
                float* op = out + (size_t)n2 * (TT * HH)
                                + (size_t)(t - 31 + s) * HH + wg * 8 + hc4 * 4;
                *(float4*)op = v;
            }
        }
        // ---- issue x prefetch for t+1 (drained by next poll's vmcnt(0))
        if (t + 1 < TT) {
            const f16* xp = xptr + (size_t)(t + 1) * DD;
            #pragma unroll
            for (int ks = 0; ks < 16; ++ks)
                xf[ks] = *(const u32x4*)(xp + ks * 32);
        }
    }
}

// ---- launch --------------------------------------------------------------

extern "C" void kernel_launch(void* const* d_in, const int* in_sizes, int n_in,
                              void* d_out, int out_size, void* d_ws, size_t ws_size,
                              hipStream_t stream)
{
    (void)in_sizes; (void)n_in; (void)out_size; (void)ws_size;
    const float* x  = (const float*)d_in[0];
    const float* h0 = (const float*)d_in[1];
    const float* Wx = (const float*)d_in[2];
    const float* Wh = (const float*)d_in[3];
    const float* b  = (const float*)d_in[4];
    float* out = (float*)d_out;

    char* ws = (char*)d_ws;
    u32* flags = (u32*)ws;                               // 4 KiB reserved
    f16* x16   = (f16*)(ws + (4 << 10));                 // 32 MiB
    f16* Wxp   = (f16*)(ws + (4 << 10) + (32 << 20));    // 2 MiB
    f16* Whp   = (f16*)(ws + (4 << 10) + (34 << 20));    // 2 MiB
    f16* hbuf  = (f16*)(ws + (4 << 10) + (36 << 20));    // 2 x 64 KiB

    hipMemsetAsync(flags, 0, 4096, stream);
    k_cast_x<<<8192, 256, 0, stream>>>(x, x16);
    k_perm_w<<<4096, 256, 0, stream>>>(Wx, Wxp);
    k_perm_w<<<4096, 256, 0, stream>>>(Wh, Whp);
    k_h0<<<64, 256, 0, stream>>>(h0, hbuf + NBHH);       // buffer 1 = h_{-1}
    k_lstm<<<NWG, 256, 0, stream>>>(x16, Wxp, Whp, b, hbuf, flags, out);
}

// Round 7
// 6559.747 us; speedup vs baseline: 1.0351x; 1.0351x over previous
//
#include <hip/hip_runtime.h>
#include <cstdint>

typedef _Float16 f16;
typedef f16      f16x8 __attribute__((ext_vector_type(8)));
typedef float    f32x4 __attribute__((ext_vector_type(4)));
typedef uint32_t u32;
typedef u32      u32x4 __attribute__((ext_vector_type(4)));

#define NB    32
#define TT    1024
#define DD    512
#define HH    512
#define NWG   64
// 4 row-groups x 8 rows; 16 WGs per group; 128 gate cols per WG.
// Per-group h buffer: [2 parity][8][512] f16 = 2 x 4096 elems.

__device__ __forceinline__ float fsig(float x) {
    return __builtin_amdgcn_rcpf(1.0f + __expf(-x));
}
__device__ __forceinline__ float ftanh(float x) {
    return 1.0f - 2.0f * __builtin_amdgcn_rcpf(__expf(2.0f * x) + 1.0f);
}

// ---- setup kernels -------------------------------------------------------

__global__ void k_cast_x(const float* __restrict__ x, f16* __restrict__ x16) {
    int i = (blockIdx.x * 256 + threadIdx.x) * 8;
    float4 a = *(const float4*)(x + i);
    float4 c = *(const float4*)(x + i + 4);
    f16x8 v;
    v[0] = (f16)a.x; v[1] = (f16)a.y; v[2] = (f16)a.z; v[3] = (f16)a.w;
    v[4] = (f16)c.x; v[5] = (f16)c.y; v[6] = (f16)c.z; v[7] = (f16)c.w;
    *(f16x8*)(x16 + i) = v;
}

// W (512 x 2048 row-major) -> Wp[P][k] f16 with
// P = wgi*128 + w*32 + ct*16 + lc ; hcol = wgi*32 + w*8 + ct*4 + (lc>>2);
// col2048 = (lc&3)*512 + hcol.
__global__ void k_perm_w(const float* __restrict__ W, f16* __restrict__ Wp) {
    int tid = blockIdx.x * 256 + threadIdx.x;   // 2048*512
    int P = tid >> 9, k = tid & 511;
    int lc = P & 15, ct = (P >> 4) & 1, w = (P >> 5) & 3, wgi = P >> 7;
    int hcol = wgi * 32 + w * 8 + ct * 4 + (lc >> 2);
    int col  = (lc & 3) * 512 + hcol;
    Wp[tid] = (f16)W[k * 2048 + col];
}

// h0 row n -> group n>>3, local row n&7, parity-1 buffer (consumed at t=0).
__global__ void k_h0(const float* __restrict__ h0, f16* __restrict__ hb) {
    int i = blockIdx.x * 256 + threadIdx.x;     // 32*512
    int n = i >> 9, hc = i & 511;
    int g = n >> 3, r = n & 7;
    hb[(size_t)g * 8192 + 4096 + r * 512 + hc] = (f16)h0[i];
}

// ---- persistent LSTM kernel ---------------------------------------------
// 64 WGs x 256 threads = 4 independent row-groups x 16 WGs. Protocol per
// group identical to R5: monotone per-WG flags, dual-parity h, producer
// sc0sc1 write-through + drain + flag, consumer coalesced sc0sc1 stage.

__global__ void __launch_bounds__(256, 1) k_lstm(
    const f16* __restrict__ x16, const f16* __restrict__ Wxp,
    const f16* __restrict__ Whp, const float* __restrict__ bb,
    f16* hbuf, u32* flags, float* __restrict__ out)
{
    __shared__ unsigned char lds_h[16384];   // [16 rows][1024B], rows 8-15 = 0
    __shared__ u32           lds_pub[256];   // 8 rows x 32 hcols
    __shared__ float         lds_out[8192];  // 32 steps x 8 rows x 32 hcols

    const int wg  = blockIdx.x;
    const int g   = wg >> 4;                 // row group (rows 8g..8g+8)
    const int wgi = wg & 15;                 // WG within group
    const int tid = threadIdx.x;
    const int w   = tid >> 6;
    const int l   = tid & 63;
    const int lq  = l >> 4, lc = l & 15;

    const int gate = lc & 3, j_in = lc >> 2;
    const int rm   = l & 3;

    // two 16-col tiles per wave
    float bv[2];
    #pragma unroll
    for (int ct = 0; ct < 2; ++ct)
        bv[ct] = bb[gate * 512 + wgi * 32 + w * 8 + ct * 4 + j_in];

    // Wh and Wx fragments resident in VGPRs (2 col-tiles x 16 k-slices).
    f16x8 Bh[2][16], Bx[2][16];
    #pragma unroll
    for (int ct = 0; ct < 2; ++ct) {
        const size_t colp = (size_t)(wgi * 128 + w * 32 + ct * 16 + lc);
        const f16* ph = Whp + colp * 512 + lq * 8;
        const f16* px = Wxp + colp * 512 + lq * 8;
        #pragma unroll
        for (int ks = 0; ks < 16; ++ks) {
            Bh[ct][ks] = *(const f16x8*)(ph + ks * 32);
            Bx[ct][ks] = *(const f16x8*)(px + ks * 32);
        }
    }

    const int arowx = g * 8 + (lc & 7);      // x A-frag row (dup for lc>=8)
    const f16* xptr = x16 + (size_t)arowx * (TT * DD) + lq * 8;

    f16* hgrp = hbuf + (size_t)g * 8192;     // group h base (2 x 4096 elems)
    u32* flgrp = flags + g * 16;

    // zero LDS rows 8-15 once (A-frag rows 8-15 read zeros forever)
    *(u32x4*)&lds_h[8192 + tid * 32]      = u32x4{0, 0, 0, 0};
    *(u32x4*)&lds_h[8192 + tid * 32 + 16] = u32x4{0, 0, 0, 0};
    __syncthreads();

    float c_reg[2][4] = {{0.f,0.f,0.f,0.f},{0.f,0.f,0.f,0.f}};

    for (int t = 0; t < TT; ++t) {
        // ---- x_t @ Wx + b (plain cached loads; off the sync chain)
        f32x4 acc0 = {bv[0], bv[0], bv[0], bv[0]};
        f32x4 acc1 = {bv[1], bv[1], bv[1], bv[1]};
        {
            const f16* xp = xptr + (size_t)t * DD;
            #pragma unroll
            for (int ks = 0; ks < 16; ++ks) {
                f16x8 ax = *(const f16x8*)(xp + ks * 32);
                acc0 = __builtin_amdgcn_mfma_f32_16x16x32_f16(ax, Bx[0][ks], acc0, 0, 0, 0);
                acc1 = __builtin_amdgcn_mfma_f32_16x16x32_f16(ax, Bx[1][ks], acc1, 0, 0, 0);
            }
        }
        // ---- poll this group's 16 flags (one 64B line)
        if (t) {
            const u32* fl = flgrp + (l & 15);
            int guard = 0;
            for (;;) {
                u32 f;
                asm volatile("global_load_dword %0, %1, off sc0 sc1"
                             : "=v"(f) : "v"(fl));
                asm volatile("s_waitcnt vmcnt(0)" ::: "memory");
                if (__all(f >= (u32)t) || ++guard > (1 << 20)) break;
            }
        }
        __builtin_amdgcn_sched_barrier(0);
        // ---- stage group h (8KB): 256 threads x 32B, coalesced sc0sc1
        {
            const char* gp = (const char*)(hgrp + ((t & 1) ? 0 : 4096)) + tid * 32;
            u32x4 h0v, h1v;
            asm volatile("global_load_dwordx4 %0, %1, off sc0 sc1" : "=v"(h0v) : "v"(gp));
            asm volatile("global_load_dwordx4 %0, %1, off offset:16 sc0 sc1" : "=v"(h1v) : "v"(gp));
            asm volatile("s_waitcnt vmcnt(0)" ::: "memory");
            __builtin_amdgcn_sched_barrier(0);
            const int row   = tid >> 5;
            const int inrow = (tid & 31) * 32;
            const int swz   = (row & 7) << 4;
            *(u32x4*)&lds_h[row * 1024 + ((inrow)      ^ swz)] = h0v;
            *(u32x4*)&lds_h[row * 1024 + ((inrow + 16) ^ swz)] = h1v;
        }
        __syncthreads();
        // ---- h_{t-1} @ Wh from LDS (A rows 8-15 are zeros)
        {
            const int baseA = lc * 1024;
            const int swz   = (lc & 7) << 4;
            #pragma unroll
            for (int ks = 0; ks < 16; ++ks) {
                int inrowA = lq * 16 + ks * 64;
                u32x4 a = *(const u32x4*)&lds_h[baseA + (inrowA ^ swz)];
                f16x8 af = __builtin_bit_cast(f16x8, a);
                acc0 = __builtin_amdgcn_mfma_f32_16x16x32_f16(af, Bh[0][ks], acc0, 0, 0, 0);
                acc1 = __builtin_amdgcn_mfma_f32_16x16x32_f16(af, Bh[1][ks], acc1, 0, 0, 0);
            }
        }
        // ---- gates for both col-tiles (quad-redundant c state)
        #pragma unroll
        for (int ct = 0; ct < 2; ++ct) {
            f32x4 acc = ct ? acc1 : acc0;
            float hv = 0.f;
            #pragma unroll
            for (int r = 0; r < 4; ++r) {
                float av = acc[r];
                int base = l & ~3;
                float ai = __shfl(av, base | 0, 64);
                float af_ = __shfl(av, base | 1, 64);
                float ao = __shfl(av, base | 2, 64);
                float ag = __shfl(av, base | 3, 64);
                float ig = fsig(ai), fg = fsig(af_), og = fsig(ao), gg = ftanh(ag);
                float cn = fg * c_reg[ct][r] + ig * gg;
                c_reg[ct][r] = cn;
                float h = og * ftanh(cn);
                if (r == rm) hv = h;
            }
            if (lq < 2) {                      // valid rows 0..7 only
                int row_local = lq * 4 + rm;
                int hcl = w * 8 + ct * 4 + j_in;
                f16 h16 = (f16)hv;
                lds_pub[row_local * 32 + hcl] = (u32)__builtin_bit_cast(unsigned short, h16);
                lds_out[(t & 31) * 256 + row_local * 32 + hcl] = hv;
            }
        }
        __syncthreads();
        // ---- wave0: publish 8 rows x 64B (full lines), drain, flag
        if (w == 0) {
            if (tid < 32) {
                const int row = tid >> 2, quad = tid & 3;
                const u32* pp = lds_pub + row * 32 + quad * 8;
                u32 p0 = (pp[0] & 0xffffu) | (pp[1] << 16);
                u32 p1 = (pp[2] & 0xffffu) | (pp[3] << 16);
                u32 p2 = (pp[4] & 0xffffu) | (pp[5] << 16);
                u32 p3 = (pp[6] & 0xffffu) | (pp[7] << 16);
                u32x4 pv = {p0, p1, p2, p3};
                f16* hdst = hgrp + ((t & 1) ? 4096 : 0) + row * 512 + wgi * 32 + quad * 8;
                asm volatile("global_store_dwordx4 %0, %1, off sc0 sc1"
                             :: "v"(hdst), "v"(pv) : "memory");
            }
            asm volatile("s_waitcnt vmcnt(0)" ::: "memory");
            if (tid == 0) {
                u32 fv = (u32)(t + 1);
                u32* mf = flgrp + wgi;
                asm volatile("global_store_dword %0, %1, off sc0 sc1"
                             :: "v"(mf), "v"(fv) : "memory");
            }
        }
        // ---- flush 32 steps of out (plain cached float4, off hot path)
        if ((t & 31) == 31) {
            #pragma unroll
            for (int k2 = 0; k2 < 8; ++k2) {
                int tau = tid + 256 * k2;          // s*64 + r*8 + q
                int s = tau >> 6, r = (tau >> 3) & 7, q = tau & 7;
                float4 v = *(const float4*)&lds_out[s * 256 + r * 32 + q * 4];
                float* op = out + (size_t)(g * 8 + r) * (TT * HH)
                                + (size_t)(t - 31 + s) * HH + wgi * 32 + q * 4;
                *(float4*)op = v;
            }
        }
    }
}

// ---- launch --------------------------------------------------------------

extern "C" void kernel_launch(void* const* d_in, const int* in_sizes, int n_in,
                              void* d_out, int out_size, void* d_ws, size_t ws_size,
                              hipStream_t stream)
{
    (void)in_sizes; (void)n_in; (void)out_size; (void)ws_size;
    const float* x  = (const float*)d_in[0];
    const float* h0 = (const float*)d_in[1];
    const float* Wx = (const float*)d_in[2];
    const float* Wh = (const float*)d_in[3];
    const float* b  = (const float*)d_in[4];
    float* out = (float*)d_out;

    char* ws = (char*)d_ws;
    u32* flags = (u32*)ws;                               // 4 KiB reserved
    f16* x16   = (f16*)(ws + (4 << 10));                 // 32 MiB
    f16* Wxp   = (f16*)(ws + (4 << 10) + (32 << 20));    // 2 MiB
    f16* Whp   = (f16*)(ws + (4 << 10) + (34 << 20));    // 2 MiB
    f16* hbuf  = (f16*)(ws + (4 << 10) + (36 << 20));    // 4 grp x 2 x 8KB

    hipMemsetAsync(flags, 0, 4096, stream);
    k_cast_x<<<8192, 256, 0, stream>>>(x, x16);
    k_perm_w<<<4096, 256, 0, stream>>>(Wx, Wxp);
    k_perm_w<<<4096, 256, 0, stream>>>(Wh, Whp);
    k_h0<<<64, 256, 0, stream>>>(h0, hbuf);              // parity-1 per group
    k_lstm<<<NWG, 256, 0, stream>>>(x16, Wxp, Whp, b, hbuf, flags, out);
}